// Round 1
// baseline (1177.762 us; speedup 1.0000x reference)
//
#include <hip/hip_runtime.h>
#include <math.h>

#define NN 50000
#define EE 800000
#define HH 4
#define CC 64
#define DE 16
#define GG 64
#define HC 256          // H*C
#define NEG 0.2f
#define EPSV 1e-5f

// float atomic max via sign-split int atomics. Works with init bits 0xFFFFFFFF
// (acts like -inf: signed -1 loses to any >=0 via atomicMax; unsigned max loses
// to any negative via atomicMin).
__device__ __forceinline__ void atomicMaxF(float* addr, float v) {
  if (!(__float_as_uint(v) & 0x80000000u)) {
    atomicMax((int*)addr, __float_as_int(v));
  } else {
    atomicMin((unsigned int*)addr, __float_as_uint(v));
  }
}

// K0: fold attention vectors through the projections.
// u_src[k][h] = sum_c W[k][h*C+c] * att_src[h][c]   (layout [k*4+h])
// v_edge[d][h] = sum_c We[d][h*C+c] * att_edge[h][c]
__global__ __launch_bounds__(256) void k_prep(
    const float* __restrict__ W, const float* __restrict__ We,
    const float* __restrict__ as_, const float* __restrict__ ad_,
    const float* __restrict__ ae_,
    float* __restrict__ u_src, float* __restrict__ u_dst,
    float* __restrict__ v_edge) {
  int t = threadIdx.x;
  int k = t >> 2, h = t & 3;
  float s1 = 0.f, s2 = 0.f;
  for (int c = 0; c < CC; ++c) {
    float w = W[k * HC + h * CC + c];
    s1 += w * as_[h * CC + c];
    s2 += w * ad_[h * CC + c];
  }
  u_src[t] = s1;
  u_dst[t] = s2;
  if (t < DE * HH) {
    int d = t >> 2, hh = t & 3;
    float s3 = 0.f;
    for (int c = 0; c < CC; ++c) s3 += We[d * HC + hh * CC + c] * ae_[hh * CC + c];
    v_edge[t] = s3;
  }
}

// K1: x[n][hc] = sum_k node[n][k] * W[k][hc]. Each wave owns 64 output cols
// (W column slice in 64 VGPRs); node row broadcast via readlane. No LDS.
__global__ __launch_bounds__(256) void k_xproj(
    const float* __restrict__ node, const float* __restrict__ W,
    float* __restrict__ x) {
  int lane = threadIdx.x & 63;
  int wid = threadIdx.x >> 6;
  int hc = wid * 64 + lane;
  float wcol[CC];
#pragma unroll
  for (int k = 0; k < CC; ++k) wcol[k] = W[k * HC + hc];
  for (int n = blockIdx.x; n < NN; n += gridDim.x) {
    float nval = node[n * CC + lane];
    float acc = 0.f;
#pragma unroll
    for (int k = 0; k < CC; ++k) {
      float s = __uint_as_float(__builtin_amdgcn_readlane(__float_as_uint(nval), k));
      acc += s * wcol[k];
    }
    x[n * HC + hc] = acc;
  }
}

// K1b: per-node attention logits a_src[n][h], a_dst[n][h] via the folded u mats.
__global__ __launch_bounds__(256) void k_attn_node(
    const float* __restrict__ node, const float* __restrict__ u_src,
    const float* __restrict__ u_dst, float* __restrict__ a_src,
    float* __restrict__ a_dst) {
  __shared__ float us[HC], ud[HC];
  int t = threadIdx.x;
  us[t] = u_src[t];
  ud[t] = u_dst[t];
  __syncthreads();
  int n = blockIdx.x * 256 + t;
  if (n >= NN) return;
  const float4* n4 = (const float4*)(node + n * CC);
  float aS[4] = {0, 0, 0, 0}, aD[4] = {0, 0, 0, 0};
#pragma unroll
  for (int kk = 0; kk < 16; ++kk) {
    float4 nv = n4[kk];
    float nvs[4] = {nv.x, nv.y, nv.z, nv.w};
#pragma unroll
    for (int j = 0; j < 4; ++j) {
      int k = kk * 4 + j;
#pragma unroll
      for (int h = 0; h < 4; ++h) {
        aS[h] += nvs[j] * us[k * 4 + h];
        aD[h] += nvs[j] * ud[k * 4 + h];
      }
    }
  }
  *(float4*)(a_src + n * 4) = make_float4(aS[0], aS[1], aS[2], aS[3]);
  *(float4*)(a_dst + n * 4) = make_float4(aD[0], aD[1], aD[2], aD[3]);
}

// K2: per-edge alpha = lrelu(a_src[src]+a_dst[dst]+edge_attr@v), atomic segment max.
__global__ __launch_bounds__(256) void k_alpha(
    const float* __restrict__ edge_attr, const int* __restrict__ ei,
    const float* __restrict__ a_src, const float* __restrict__ a_dst,
    const float* __restrict__ v_edge, float* __restrict__ alpha,
    float* __restrict__ amax) {
  __shared__ float vs[DE * HH];
  int t = threadIdx.x;
  if (t < DE * HH) vs[t] = v_edge[t];
  __syncthreads();
  int e = blockIdx.x * 256 + t;
  if (e >= EE) return;
  const float4* ea4 = (const float4*)(edge_attr + (size_t)e * DE);
  float ae[4] = {0, 0, 0, 0};
#pragma unroll
  for (int dd = 0; dd < 4; ++dd) {
    float4 ev = ea4[dd];
    float evs[4] = {ev.x, ev.y, ev.z, ev.w};
#pragma unroll
    for (int j = 0; j < 4; ++j) {
      int d = dd * 4 + j;
#pragma unroll
      for (int h = 0; h < 4; ++h) ae[h] += evs[j] * vs[d * 4 + h];
    }
  }
  int sn = ei[e], dn = ei[EE + e];
  float4 as4 = *(const float4*)(a_src + sn * 4);
  float4 ad4 = *(const float4*)(a_dst + dn * 4);
  float asv[4] = {as4.x, as4.y, as4.z, as4.w};
  float adv[4] = {ad4.x, ad4.y, ad4.z, ad4.w};
  float al[4];
#pragma unroll
  for (int h = 0; h < 4; ++h) {
    float a = asv[h] + adv[h] + ae[h];
    al[h] = a >= 0.f ? a : NEG * a;
    atomicMaxF(amax + dn * 4 + h, al[h]);
  }
  *(float4*)(alpha + (size_t)e * 4) = make_float4(al[0], al[1], al[2], al[3]);
}

// K3: ex = exp(alpha - amax[dst]) (in place), atomic denom sum.
__global__ __launch_bounds__(256) void k_expden(
    const int* __restrict__ ei, const float* __restrict__ amax,
    float* __restrict__ alpha, float* __restrict__ denom) {
  int e = blockIdx.x * 256 + threadIdx.x;
  if (e >= EE) return;
  int dn = ei[EE + e];
  float4 al = *(const float4*)(alpha + (size_t)e * 4);
  float4 mx = *(const float4*)(amax + dn * 4);
  float e0 = expf(al.x - mx.x);
  float e1 = expf(al.y - mx.y);
  float e2 = expf(al.z - mx.z);
  float e3 = expf(al.w - mx.w);
  *(float4*)(alpha + (size_t)e * 4) = make_float4(e0, e1, e2, e3);
  atomicAdd(denom + dn * 4 + 0, e0);
  atomicAdd(denom + dn * 4 + 1, e1);
  atomicAdd(denom + dn * 4 + 2, e2);
  atomicAdd(denom + dn * 4 + 3, e3);
}

// K4: att output + head-mean-folded weighted scatter into out_acc (N,64).
// One wave per edge, lane = channel.
__global__ __launch_bounds__(256) void k_scatter(
    const int* __restrict__ ei, const float* __restrict__ ex,
    const float* __restrict__ denom, const float* __restrict__ x,
    float* __restrict__ out_acc, float* __restrict__ att_out) {
  int lane = threadIdx.x & 63;
  int e = blockIdx.x * 4 + (threadIdx.x >> 6);
  int sn = ei[e], dn = ei[EE + e];
  float4 e4 = *(const float4*)(ex + (size_t)e * 4);
  float4 d4 = *(const float4*)(denom + dn * 4);
  float a0 = e4.x / (d4.x + 1e-16f);
  float a1 = e4.y / (d4.y + 1e-16f);
  float a2 = e4.z / (d4.z + 1e-16f);
  float a3 = e4.w / (d4.w + 1e-16f);
  if (lane == 0) *(float4*)(att_out + (size_t)e * 4) = make_float4(a0, a1, a2, a3);
  const float* xs = x + (size_t)sn * HC;
  float m = 0.25f * (a0 * xs[lane] + a1 * xs[64 + lane] + a2 * xs[128 + lane] +
                     a3 * xs[192 + lane]);
  atomicAdd(out_acc + (size_t)dn * CC + lane, m);
}

// K5: add bias, per-group sums + count. One wave per node.
__global__ __launch_bounds__(256) void k_gsum(
    const int* __restrict__ batch, const float* __restrict__ bias,
    float* __restrict__ out_acc, float* __restrict__ gsum,
    float* __restrict__ cnt) {
  int lane = threadIdx.x & 63;
  int n = blockIdx.x * 4 + (threadIdx.x >> 6);
  float v = out_acc[(size_t)n * CC + lane] + bias[lane];
  out_acc[(size_t)n * CC + lane] = v;
  int g = batch[n];
  atomicAdd(gsum + g * CC + lane, v);
  if (lane == 0) atomicAdd(cnt + g, 1.0f);
}

// K6: mean_s[g][c] = (gsum/cnt) * gn_scale[c]
__global__ __launch_bounds__(256) void k_mean(
    const float* __restrict__ gsum, const float* __restrict__ cnt,
    const float* __restrict__ gns, float* __restrict__ mean_s) {
  int i = blockIdx.x * 256 + threadIdx.x;
  if (i >= GG * CC) return;
  int g = i >> 6, c = i & 63;
  mean_s[i] = (gsum[i] / fmaxf(cnt[g], 1.0f)) * gns[c];
}

// K7: per-group variance sums of o = out - mean_s[g]
__global__ __launch_bounds__(256) void k_vsum(
    const int* __restrict__ batch, const float* __restrict__ out_acc,
    const float* __restrict__ mean_s, float* __restrict__ vsum) {
  int lane = threadIdx.x & 63;
  int n = blockIdx.x * 4 + (threadIdx.x >> 6);
  int g = batch[n];
  float o = out_acc[(size_t)n * CC + lane] - mean_s[g * CC + lane];
  atomicAdd(vsum + g * CC + lane, o * o);
}

// K8: normalize + affine + relu -> y
__global__ __launch_bounds__(256) void k_final(
    const int* __restrict__ batch, const float* __restrict__ out_acc,
    const float* __restrict__ mean_s, const float* __restrict__ vsum,
    const float* __restrict__ cnt, const float* __restrict__ gnw,
    const float* __restrict__ gnb, float* __restrict__ y) {
  int lane = threadIdx.x & 63;
  int n = blockIdx.x * 4 + (threadIdx.x >> 6);
  int g = batch[n];
  float var = vsum[g * CC + lane] / fmaxf(cnt[g], 1.0f);
  float o = (out_acc[(size_t)n * CC + lane] - mean_s[g * CC + lane]) /
            sqrtf(var + EPSV);
  float r = gnw[lane] * o + gnb[lane];
  y[(size_t)n * CC + lane] = fmaxf(r, 0.0f);
}

extern "C" void kernel_launch(void* const* d_in, const int* in_sizes, int n_in,
                              void* d_out, int out_size, void* d_ws, size_t ws_size,
                              hipStream_t stream) {
  const float* node = (const float*)d_in[0];
  const int* ei = (const int*)d_in[1];
  const float* eatt = (const float*)d_in[2];
  const int* batch = (const int*)d_in[3];
  const float* W = (const float*)d_in[4];
  const float* We = (const float*)d_in[5];
  const float* att_src = (const float*)d_in[6];
  const float* att_dst = (const float*)d_in[7];
  const float* att_edge = (const float*)d_in[8];
  const float* bias = (const float*)d_in[9];
  const float* gnw = (const float*)d_in[10];
  const float* gnb = (const float*)d_in[11];
  const float* gns = (const float*)d_in[12];

  float* ws = (float*)d_ws;
  size_t off = 0;
  float* x = ws + off;        off += (size_t)NN * HC;   // 12.8M
  float* alpha = ws + off;    off += (size_t)EE * HH;   // 3.2M (alpha -> ex)
  float* a_src = ws + off;    off += (size_t)NN * HH;
  float* a_dst = ws + off;    off += (size_t)NN * HH;
  float* u_src = ws + off;    off += HC;
  float* u_dst = ws + off;    off += HC;
  float* v_edge = ws + off;   off += 64;
  float* mean_s = ws + off;   off += GG * CC;
  float* zbase = ws + off;                              // ---- zero region ----
  float* denom = ws + off;    off += (size_t)NN * HH;
  float* out_acc = ws + off;  off += (size_t)NN * CC;
  float* gsum = ws + off;     off += GG * CC;
  float* vsum = ws + off;     off += GG * CC;
  float* cnt = ws + off;      off += GG;
  size_t zcount = (size_t)((ws + off) - zbase);
  float* amax = ws + off;     off += (size_t)NN * HH;   // ---- 0xFF region ----

  hipMemsetAsync(zbase, 0, zcount * sizeof(float), stream);
  hipMemsetAsync(amax, 0xFF, (size_t)NN * HH * sizeof(float), stream);

  float* y_out = (float*)d_out;
  float* att_out = (float*)d_out + (size_t)NN * CC;

  k_prep<<<1, 256, 0, stream>>>(W, We, att_src, att_dst, att_edge, u_src, u_dst,
                                v_edge);
  k_xproj<<<2048, 256, 0, stream>>>(node, W, x);
  k_attn_node<<<(NN + 255) / 256, 256, 0, stream>>>(node, u_src, u_dst, a_src,
                                                    a_dst);
  k_alpha<<<(EE + 255) / 256, 256, 0, stream>>>(eatt, ei, a_src, a_dst, v_edge,
                                                alpha, amax);
  k_expden<<<(EE + 255) / 256, 256, 0, stream>>>(ei, amax, alpha, denom);
  k_scatter<<<EE / 4, 256, 0, stream>>>(ei, alpha, denom, x, out_acc, att_out);
  k_gsum<<<NN / 4, 256, 0, stream>>>(batch, bias, out_acc, gsum, cnt);
  k_mean<<<(GG * CC + 255) / 256, 256, 0, stream>>>(gsum, cnt, gns, mean_s);
  k_vsum<<<NN / 4, 256, 0, stream>>>(batch, out_acc, mean_s, vsum);
  k_final<<<NN / 4, 256, 0, stream>>>(batch, out_acc, mean_s, vsum, cnt, gnw, gnb,
                                      y_out);
}

// Round 2
// 782.834 us; speedup vs baseline: 1.5045x; 1.5045x over previous
//
#include <hip/hip_runtime.h>
#include <math.h>

#define NN 50000
#define EE 800000
#define HH 4
#define CC 64
#define DE 16
#define GG 64
#define HC 256          // H*C
#define NEG 0.2f
#define EPSV 1e-5f

// float atomic max via sign-split int atomics. Works with init bits 0xFFFFFFFF
// (acts like -inf: signed -1 loses to any >=0 via atomicMax; unsigned max loses
// to any negative via atomicMin).
__device__ __forceinline__ void atomicMaxF(float* addr, float v) {
  if (!(__float_as_uint(v) & 0x80000000u)) {
    atomicMax((int*)addr, __float_as_int(v));
  } else {
    atomicMin((unsigned int*)addr, __float_as_uint(v));
  }
}

// K0: fold attention vectors through the projections.
// u_src[k][h] = sum_c W[k][h*C+c] * att_src[h][c]   (layout [k*4+h])
// v_edge[d][h] = sum_c We[d][h*C+c] * att_edge[h][c]
__global__ __launch_bounds__(256) void k_prep(
    const float* __restrict__ W, const float* __restrict__ We,
    const float* __restrict__ as_, const float* __restrict__ ad_,
    const float* __restrict__ ae_,
    float* __restrict__ u_src, float* __restrict__ u_dst,
    float* __restrict__ v_edge) {
  int t = threadIdx.x;
  int k = t >> 2, h = t & 3;
  float s1 = 0.f, s2 = 0.f;
  for (int c = 0; c < CC; ++c) {
    float w = W[k * HC + h * CC + c];
    s1 += w * as_[h * CC + c];
    s2 += w * ad_[h * CC + c];
  }
  u_src[t] = s1;
  u_dst[t] = s2;
  if (t < DE * HH) {
    int d = t >> 2, hh = t & 3;
    float s3 = 0.f;
    for (int c = 0; c < CC; ++c) s3 += We[d * HC + hh * CC + c] * ae_[hh * CC + c];
    v_edge[t] = s3;
  }
}

// K1: x[n][hc] = sum_k node[n][k] * W[k][hc]. Each wave owns 64 output cols
// (W column slice in 64 VGPRs); node row broadcast via readlane. No LDS.
__global__ __launch_bounds__(256) void k_xproj(
    const float* __restrict__ node, const float* __restrict__ W,
    float* __restrict__ x) {
  int lane = threadIdx.x & 63;
  int wid = threadIdx.x >> 6;
  int hc = wid * 64 + lane;
  float wcol[CC];
#pragma unroll
  for (int k = 0; k < CC; ++k) wcol[k] = W[k * HC + hc];
  for (int n = blockIdx.x; n < NN; n += gridDim.x) {
    float nval = node[n * CC + lane];
    float acc = 0.f;
#pragma unroll
    for (int k = 0; k < CC; ++k) {
      float s = __uint_as_float(__builtin_amdgcn_readlane(__float_as_uint(nval), k));
      acc += s * wcol[k];
    }
    x[n * HC + hc] = acc;
  }
}

// K1b: per-node attention logits a_src[n][h], a_dst[n][h] via the folded u mats.
__global__ __launch_bounds__(256) void k_attn_node(
    const float* __restrict__ node, const float* __restrict__ u_src,
    const float* __restrict__ u_dst, float* __restrict__ a_src,
    float* __restrict__ a_dst) {
  __shared__ float us[HC], ud[HC];
  int t = threadIdx.x;
  us[t] = u_src[t];
  ud[t] = u_dst[t];
  __syncthreads();
  int n = blockIdx.x * 256 + t;
  if (n >= NN) return;
  const float4* n4 = (const float4*)(node + n * CC);
  float aS[4] = {0, 0, 0, 0}, aD[4] = {0, 0, 0, 0};
#pragma unroll
  for (int kk = 0; kk < 16; ++kk) {
    float4 nv = n4[kk];
    float nvs[4] = {nv.x, nv.y, nv.z, nv.w};
#pragma unroll
    for (int j = 0; j < 4; ++j) {
      int k = kk * 4 + j;
#pragma unroll
      for (int h = 0; h < 4; ++h) {
        aS[h] += nvs[j] * us[k * 4 + h];
        aD[h] += nvs[j] * ud[k * 4 + h];
      }
    }
  }
  *(float4*)(a_src + n * 4) = make_float4(aS[0], aS[1], aS[2], aS[3]);
  *(float4*)(a_dst + n * 4) = make_float4(aD[0], aD[1], aD[2], aD[3]);
}

// K2: per-edge alpha = lrelu(a_src[src]+a_dst[dst]+edge_attr@v), atomic segment max.
__global__ __launch_bounds__(256) void k_alpha(
    const float* __restrict__ edge_attr, const int* __restrict__ ei,
    const float* __restrict__ a_src, const float* __restrict__ a_dst,
    const float* __restrict__ v_edge, float* __restrict__ alpha,
    float* __restrict__ amax) {
  __shared__ float vs[DE * HH];
  int t = threadIdx.x;
  if (t < DE * HH) vs[t] = v_edge[t];
  __syncthreads();
  int e = blockIdx.x * 256 + t;
  if (e >= EE) return;
  const float4* ea4 = (const float4*)(edge_attr + (size_t)e * DE);
  float ae[4] = {0, 0, 0, 0};
#pragma unroll
  for (int dd = 0; dd < 4; ++dd) {
    float4 ev = ea4[dd];
    float evs[4] = {ev.x, ev.y, ev.z, ev.w};
#pragma unroll
    for (int j = 0; j < 4; ++j) {
      int d = dd * 4 + j;
#pragma unroll
      for (int h = 0; h < 4; ++h) ae[h] += evs[j] * vs[d * 4 + h];
    }
  }
  int sn = ei[e], dn = ei[EE + e];
  float4 as4 = *(const float4*)(a_src + sn * 4);
  float4 ad4 = *(const float4*)(a_dst + dn * 4);
  float asv[4] = {as4.x, as4.y, as4.z, as4.w};
  float adv[4] = {ad4.x, ad4.y, ad4.z, ad4.w};
  float al[4];
#pragma unroll
  for (int h = 0; h < 4; ++h) {
    float a = asv[h] + adv[h] + ae[h];
    al[h] = a >= 0.f ? a : NEG * a;
    atomicMaxF(amax + dn * 4 + h, al[h]);
  }
  *(float4*)(alpha + (size_t)e * 4) = make_float4(al[0], al[1], al[2], al[3]);
}

// K3: ex = exp(alpha - amax[dst]) (in place), atomic denom sum.
__global__ __launch_bounds__(256) void k_expden(
    const int* __restrict__ ei, const float* __restrict__ amax,
    float* __restrict__ alpha, float* __restrict__ denom) {
  int e = blockIdx.x * 256 + threadIdx.x;
  if (e >= EE) return;
  int dn = ei[EE + e];
  float4 al = *(const float4*)(alpha + (size_t)e * 4);
  float4 mx = *(const float4*)(amax + dn * 4);
  float e0 = expf(al.x - mx.x);
  float e1 = expf(al.y - mx.y);
  float e2 = expf(al.z - mx.z);
  float e3 = expf(al.w - mx.w);
  *(float4*)(alpha + (size_t)e * 4) = make_float4(e0, e1, e2, e3);
  atomicAdd(denom + dn * 4 + 0, e0);
  atomicAdd(denom + dn * 4 + 1, e1);
  atomicAdd(denom + dn * 4 + 2, e2);
  atomicAdd(denom + dn * 4 + 3, e3);
}

// K4: att output + head-mean-folded weighted scatter into out_acc (N,64).
// One wave per edge, lane = channel.
__global__ __launch_bounds__(256) void k_scatter(
    const int* __restrict__ ei, const float* __restrict__ ex,
    const float* __restrict__ denom, const float* __restrict__ x,
    float* __restrict__ out_acc, float* __restrict__ att_out) {
  int lane = threadIdx.x & 63;
  int e = blockIdx.x * 4 + (threadIdx.x >> 6);
  int sn = ei[e], dn = ei[EE + e];
  float4 e4 = *(const float4*)(ex + (size_t)e * 4);
  float4 d4 = *(const float4*)(denom + dn * 4);
  float a0 = e4.x / (d4.x + 1e-16f);
  float a1 = e4.y / (d4.y + 1e-16f);
  float a2 = e4.z / (d4.z + 1e-16f);
  float a3 = e4.w / (d4.w + 1e-16f);
  if (lane == 0) *(float4*)(att_out + (size_t)e * 4) = make_float4(a0, a1, a2, a3);
  const float* xs = x + (size_t)sn * HC;
  float m = 0.25f * (a0 * xs[lane] + a1 * xs[64 + lane] + a2 * xs[128 + lane] +
                     a3 * xs[192 + lane]);
  atomicAdd(out_acc + (size_t)dn * CC + lane, m);
}

// K5: GraphNorm stats, one block per group (batch_ptr is sorted -> groups are
// contiguous node ranges; binary-search the range, reduce in registers+LDS,
// ZERO atomics). var via E[v^2] - 2*ms*E[v] + ms^2 folds the two reference
// passes into one.
__global__ __launch_bounds__(256) void k_stats(
    const int* __restrict__ batch, const float* __restrict__ out_acc,
    const float* __restrict__ bias, const float* __restrict__ gns,
    float* __restrict__ mean_s, float* __restrict__ istd) {
  int g = blockIdx.x;
  int lane = threadIdx.x & 63;
  int w = threadIdx.x >> 6;
  // lower_bound(batch, g) and lower_bound(batch, g+1)
  int lo = 0, hi = NN;
  while (lo < hi) {
    int mid = (lo + hi) >> 1;
    if (batch[mid] < g) lo = mid + 1; else hi = mid;
  }
  int start = lo;
  hi = NN;
  while (lo < hi) {
    int mid = (lo + hi) >> 1;
    if (batch[mid] < g + 1) lo = mid + 1; else hi = mid;
  }
  int end = lo;
  float b = bias[lane];
  float s1 = 0.f, s2 = 0.f;
  for (int n = start + w; n < end; n += 4) {
    float v = out_acc[(size_t)n * CC + lane] + b;
    s1 += v;
    s2 += v * v;
  }
  __shared__ float l1[4][64], l2[4][64];
  l1[w][lane] = s1;
  l2[w][lane] = s2;
  __syncthreads();
  if (w == 0) {
    s1 = l1[0][lane] + l1[1][lane] + l1[2][lane] + l1[3][lane];
    s2 = l2[0][lane] + l2[1][lane] + l2[2][lane] + l2[3][lane];
    float c = fmaxf((float)(end - start), 1.0f);
    float mean = s1 / c;
    float ms = mean * gns[lane];
    float var = s2 / c - 2.f * ms * mean + ms * ms;
    mean_s[g * CC + lane] = ms;
    istd[g * CC + lane] = rsqrtf(var + EPSV);
  }
}

// K6: normalize + affine + relu -> y
__global__ __launch_bounds__(256) void k_final(
    const int* __restrict__ batch, const float* __restrict__ out_acc,
    const float* __restrict__ bias, const float* __restrict__ mean_s,
    const float* __restrict__ istd, const float* __restrict__ gnw,
    const float* __restrict__ gnb, float* __restrict__ y) {
  int lane = threadIdx.x & 63;
  int n = blockIdx.x * 4 + (threadIdx.x >> 6);
  int g = batch[n];
  float v = out_acc[(size_t)n * CC + lane] + bias[lane];
  float o = (v - mean_s[g * CC + lane]) * istd[g * CC + lane];
  float r = gnw[lane] * o + gnb[lane];
  y[(size_t)n * CC + lane] = fmaxf(r, 0.0f);
}

extern "C" void kernel_launch(void* const* d_in, const int* in_sizes, int n_in,
                              void* d_out, int out_size, void* d_ws, size_t ws_size,
                              hipStream_t stream) {
  const float* node = (const float*)d_in[0];
  const int* ei = (const int*)d_in[1];
  const float* eatt = (const float*)d_in[2];
  const int* batch = (const int*)d_in[3];
  const float* W = (const float*)d_in[4];
  const float* We = (const float*)d_in[5];
  const float* att_src = (const float*)d_in[6];
  const float* att_dst = (const float*)d_in[7];
  const float* att_edge = (const float*)d_in[8];
  const float* bias = (const float*)d_in[9];
  const float* gnw = (const float*)d_in[10];
  const float* gnb = (const float*)d_in[11];
  const float* gns = (const float*)d_in[12];

  float* ws = (float*)d_ws;
  size_t off = 0;
  float* x = ws + off;        off += (size_t)NN * HC;   // 12.8M
  float* alpha = ws + off;    off += (size_t)EE * HH;   // 3.2M (alpha -> ex)
  float* a_src = ws + off;    off += (size_t)NN * HH;
  float* a_dst = ws + off;    off += (size_t)NN * HH;
  float* u_src = ws + off;    off += HC;
  float* u_dst = ws + off;    off += HC;
  float* v_edge = ws + off;   off += 64;
  float* mean_s = ws + off;   off += GG * CC;
  float* istd = ws + off;     off += GG * CC;
  float* zbase = ws + off;                              // ---- zero region ----
  float* denom = ws + off;    off += (size_t)NN * HH;
  float* out_acc = ws + off;  off += (size_t)NN * CC;
  size_t zcount = (size_t)((ws + off) - zbase);
  float* amax = ws + off;     off += (size_t)NN * HH;   // ---- 0xFF region ----

  hipMemsetAsync(zbase, 0, zcount * sizeof(float), stream);
  hipMemsetAsync(amax, 0xFF, (size_t)NN * HH * sizeof(float), stream);

  float* y_out = (float*)d_out;
  float* att_out = (float*)d_out + (size_t)NN * CC;

  k_prep<<<1, 256, 0, stream>>>(W, We, att_src, att_dst, att_edge, u_src, u_dst,
                                v_edge);
  k_xproj<<<2048, 256, 0, stream>>>(node, W, x);
  k_attn_node<<<(NN + 255) / 256, 256, 0, stream>>>(node, u_src, u_dst, a_src,
                                                    a_dst);
  k_alpha<<<(EE + 255) / 256, 256, 0, stream>>>(eatt, ei, a_src, a_dst, v_edge,
                                                alpha, amax);
  k_expden<<<(EE + 255) / 256, 256, 0, stream>>>(ei, amax, alpha, denom);
  k_scatter<<<EE / 4, 256, 0, stream>>>(ei, alpha, denom, x, out_acc, att_out);
  k_stats<<<GG, 256, 0, stream>>>(batch, out_acc, bias, gns, mean_s, istd);
  k_final<<<NN / 4, 256, 0, stream>>>(batch, out_acc, bias, mean_s, istd, gnw,
                                      gnb, y_out);
}

// Round 3
// 648.409 us; speedup vs baseline: 1.8164x; 1.2073x over previous
//
#include <hip/hip_runtime.h>
#include <math.h>

#define NN 50000
#define EE 800000
#define HH 4
#define CC 64
#define DE 16
#define GG 64
#define HC 256          // H*C
#define NEG 0.2f
#define EPSV 1e-5f
#define NINF (-1e30f)

// K0: fold attention vectors through the projections.
// u_src[k][h] = sum_c W[k][h*C+c] * att_src[h][c]   (layout [k*4+h])
// v_edge[d][h] = sum_c We[d][h*C+c] * att_edge[h][c]
__global__ __launch_bounds__(256) void k_prep(
    const float* __restrict__ W, const float* __restrict__ We,
    const float* __restrict__ as_, const float* __restrict__ ad_,
    const float* __restrict__ ae_,
    float* __restrict__ u_src, float* __restrict__ u_dst,
    float* __restrict__ v_edge) {
  int t = threadIdx.x;
  int k = t >> 2, h = t & 3;
  float s1 = 0.f, s2 = 0.f;
  for (int c = 0; c < CC; ++c) {
    float w = W[k * HC + h * CC + c];
    s1 += w * as_[h * CC + c];
    s2 += w * ad_[h * CC + c];
  }
  u_src[t] = s1;
  u_dst[t] = s2;
  if (t < DE * HH) {
    int d = t >> 2, hh = t & 3;
    float s3 = 0.f;
    for (int c = 0; c < CC; ++c) s3 += We[d * HC + hh * CC + c] * ae_[hh * CC + c];
    v_edge[t] = s3;
  }
}

// K1: x[n][hc] = sum_k node[n][k] * W[k][hc]. Each wave owns 64 output cols
// (W column slice in 64 VGPRs); node row broadcast via readlane. No LDS.
__global__ __launch_bounds__(256) void k_xproj(
    const float* __restrict__ node, const float* __restrict__ W,
    float* __restrict__ x) {
  int lane = threadIdx.x & 63;
  int wid = threadIdx.x >> 6;
  int hc = wid * 64 + lane;
  float wcol[CC];
#pragma unroll
  for (int k = 0; k < CC; ++k) wcol[k] = W[k * HC + hc];
  for (int n = blockIdx.x; n < NN; n += gridDim.x) {
    float nval = node[n * CC + lane];
    float acc = 0.f;
#pragma unroll
    for (int k = 0; k < CC; ++k) {
      float s = __uint_as_float(__builtin_amdgcn_readlane(__float_as_uint(nval), k));
      acc += s * wcol[k];
    }
    x[n * HC + hc] = acc;
  }
}

// K1b: per-node attention logits a_src[n][h], a_dst[n][h] via the folded u mats.
__global__ __launch_bounds__(256) void k_attn_node(
    const float* __restrict__ node, const float* __restrict__ u_src,
    const float* __restrict__ u_dst, float* __restrict__ a_src,
    float* __restrict__ a_dst) {
  __shared__ float us[HC], ud[HC];
  int t = threadIdx.x;
  us[t] = u_src[t];
  ud[t] = u_dst[t];
  __syncthreads();
  int n = blockIdx.x * 256 + t;
  if (n >= NN) return;
  const float4* n4 = (const float4*)(node + n * CC);
  float aS[4] = {0, 0, 0, 0}, aD[4] = {0, 0, 0, 0};
#pragma unroll
  for (int kk = 0; kk < 16; ++kk) {
    float4 nv = n4[kk];
    float nvs[4] = {nv.x, nv.y, nv.z, nv.w};
#pragma unroll
    for (int j = 0; j < 4; ++j) {
      int k = kk * 4 + j;
#pragma unroll
      for (int h = 0; h < 4; ++h) {
        aS[h] += nvs[j] * us[k * 4 + h];
        aD[h] += nvs[j] * ud[k * 4 + h];
      }
    }
  }
  *(float4*)(a_src + n * 4) = make_float4(aS[0], aS[1], aS[2], aS[3]);
  *(float4*)(a_dst + n * 4) = make_float4(aD[0], aD[1], aD[2], aD[3]);
}

// K2: per-edge PARTIAL logit (a_src[src] + edge_attr@v; dst term + lrelu added
// later, wave-uniform, in k_gat) + dst histogram. No float atomics.
__global__ __launch_bounds__(256) void k_edge1(
    const float* __restrict__ edge_attr, const int* __restrict__ ei,
    const float* __restrict__ a_src, const float* __restrict__ v_edge,
    float* __restrict__ partial, int* __restrict__ hist) {
  __shared__ float vs[DE * HH];
  int t = threadIdx.x;
  if (t < DE * HH) vs[t] = v_edge[t];
  __syncthreads();
  int e = blockIdx.x * 256 + t;
  if (e >= EE) return;
  const float4* ea4 = (const float4*)(edge_attr + (size_t)e * DE);
  float ae[4] = {0, 0, 0, 0};
#pragma unroll
  for (int dd = 0; dd < 4; ++dd) {
    float4 ev = ea4[dd];
    float evs[4] = {ev.x, ev.y, ev.z, ev.w};
#pragma unroll
    for (int j = 0; j < 4; ++j) {
      int d = dd * 4 + j;
#pragma unroll
      for (int h = 0; h < 4; ++h) ae[h] += evs[j] * vs[d * 4 + h];
    }
  }
  int sn = ei[e], dn = ei[EE + e];
  float4 as4 = *(const float4*)(a_src + (size_t)sn * 4);
  *(float4*)(partial + (size_t)e * 4) =
      make_float4(as4.x + ae[0], as4.y + ae[1], as4.z + ae[2], as4.w + ae[3]);
  atomicAdd(&hist[dn], 1);
}

// K3: single-workgroup exclusive scan of the 50K-bin histogram -> ptr, cursor.
#define SCAN_T 1024
#define CHUNK 49  // 1024*49 = 50176 >= NN
__global__ __launch_bounds__(1024) void k_scan(
    const int* __restrict__ hist, int* __restrict__ ptr,
    int* __restrict__ cursor) {
  __shared__ int sums[SCAN_T];
  int t = threadIdx.x;
  int base = t * CHUNK;
  int s = 0;
  for (int i = 0; i < CHUNK; ++i) {
    int idx = base + i;
    if (idx < NN) s += hist[idx];
  }
  sums[t] = s;
  __syncthreads();
  for (int d = 1; d < SCAN_T; d <<= 1) {
    int v = (t >= d) ? sums[t - d] : 0;
    __syncthreads();
    sums[t] += v;
    __syncthreads();
  }
  int run = (t == 0) ? 0 : sums[t - 1];
  for (int i = 0; i < CHUNK; ++i) {
    int idx = base + i;
    if (idx < NN) {
      ptr[idx] = run;
      cursor[idx] = run;
      run += hist[idx];
    }
  }
  if (t == SCAN_T - 1) ptr[NN] = sums[SCAN_T - 1];
}

// K4: scatter edge ids into dst-sorted order.
__global__ __launch_bounds__(256) void k_permute(
    const int* __restrict__ ei, int* __restrict__ cursor,
    int* __restrict__ eid) {
  int e = blockIdx.x * 256 + threadIdx.x;
  if (e >= EE) return;
  int dn = ei[EE + e];
  int pos = atomicAdd(&cursor[dn], 1);
  eid[pos] = e;
}

// K5: one wave per dst node. Softmax over its edge run (no atomics) + head-
// folded weighted gather of x[src], one coalesced 256B store per node.
__global__ __launch_bounds__(256) void k_gat(
    const int* __restrict__ ptr, const int* __restrict__ eid,
    const int* __restrict__ ei, const float* __restrict__ partial,
    const float* __restrict__ a_dst, const float* __restrict__ x,
    float* __restrict__ out_acc, float* __restrict__ att_out) {
  int lane = threadIdx.x & 63;
  int w = threadIdx.x >> 6;
  int v = blockIdx.x * 4 + w;
  if (v >= NN) return;
  int start = ptr[v], end = ptr[v + 1];
  float4 ad = *(const float4*)(a_dst + (size_t)v * 4);
  // pass 1: per-head max, lane-parallel
  float m0 = NINF, m1 = NINF, m2 = NINF, m3 = NINF;
  for (int j = start + lane; j < end; j += 64) {
    int e = eid[j];
    float4 p = *(const float4*)(partial + (size_t)e * 4);
    float a0 = p.x + ad.x; a0 = a0 >= 0.f ? a0 : NEG * a0;
    float a1 = p.y + ad.y; a1 = a1 >= 0.f ? a1 : NEG * a1;
    float a2 = p.z + ad.z; a2 = a2 >= 0.f ? a2 : NEG * a2;
    float a3 = p.w + ad.w; a3 = a3 >= 0.f ? a3 : NEG * a3;
    m0 = fmaxf(m0, a0); m1 = fmaxf(m1, a1);
    m2 = fmaxf(m2, a2); m3 = fmaxf(m3, a3);
  }
#pragma unroll
  for (int s = 32; s; s >>= 1) {
    m0 = fmaxf(m0, __shfl_xor(m0, s));
    m1 = fmaxf(m1, __shfl_xor(m1, s));
    m2 = fmaxf(m2, __shfl_xor(m2, s));
    m3 = fmaxf(m3, __shfl_xor(m3, s));
  }
  // pass 2: denom, lane-parallel
  float s0 = 0.f, s1 = 0.f, s2 = 0.f, s3 = 0.f;
  for (int j = start + lane; j < end; j += 64) {
    int e = eid[j];
    float4 p = *(const float4*)(partial + (size_t)e * 4);
    float a0 = p.x + ad.x; a0 = a0 >= 0.f ? a0 : NEG * a0;
    float a1 = p.y + ad.y; a1 = a1 >= 0.f ? a1 : NEG * a1;
    float a2 = p.z + ad.z; a2 = a2 >= 0.f ? a2 : NEG * a2;
    float a3 = p.w + ad.w; a3 = a3 >= 0.f ? a3 : NEG * a3;
    s0 += expf(a0 - m0); s1 += expf(a1 - m1);
    s2 += expf(a2 - m2); s3 += expf(a3 - m3);
  }
#pragma unroll
  for (int s = 32; s; s >>= 1) {
    s0 += __shfl_xor(s0, s);
    s1 += __shfl_xor(s1, s);
    s2 += __shfl_xor(s2, s);
    s3 += __shfl_xor(s3, s);
  }
  float r0 = 1.f / (s0 + 1e-16f), r1 = 1.f / (s1 + 1e-16f);
  float r2 = 1.f / (s2 + 1e-16f), r3 = 1.f / (s3 + 1e-16f);
  // pass 3: sequential over the run; gather x[src], accumulate head-folded msg
  float acc = 0.f;
  for (int j = start; j < end; ++j) {
    int e = eid[j];  // wave-uniform
    float4 p = *(const float4*)(partial + (size_t)e * 4);
    float a0 = p.x + ad.x; a0 = a0 >= 0.f ? a0 : NEG * a0;
    float a1 = p.y + ad.y; a1 = a1 >= 0.f ? a1 : NEG * a1;
    float a2 = p.z + ad.z; a2 = a2 >= 0.f ? a2 : NEG * a2;
    float a3 = p.w + ad.w; a3 = a3 >= 0.f ? a3 : NEG * a3;
    float t0 = expf(a0 - m0) * r0;
    float t1 = expf(a1 - m1) * r1;
    float t2 = expf(a2 - m2) * r2;
    float t3 = expf(a3 - m3) * r3;
    int sn = ei[e];
    const float* xs = x + (size_t)sn * HC;
    acc += t0 * xs[lane] + t1 * xs[64 + lane] + t2 * xs[128 + lane] +
           t3 * xs[192 + lane];
    if (lane == 0)
      *(float4*)(att_out + (size_t)e * 4) = make_float4(t0, t1, t2, t3);
  }
  out_acc[(size_t)v * CC + lane] = 0.25f * acc;
}

// K6: GraphNorm stats, one block per group (batch_ptr sorted -> contiguous
// ranges; binary search, register+LDS reduce, zero atomics).
__global__ __launch_bounds__(256) void k_stats(
    const int* __restrict__ batch, const float* __restrict__ out_acc,
    const float* __restrict__ bias, const float* __restrict__ gns,
    float* __restrict__ mean_s, float* __restrict__ istd) {
  int g = blockIdx.x;
  int lane = threadIdx.x & 63;
  int w = threadIdx.x >> 6;
  int lo = 0, hi = NN;
  while (lo < hi) {
    int mid = (lo + hi) >> 1;
    if (batch[mid] < g) lo = mid + 1; else hi = mid;
  }
  int start = lo;
  hi = NN;
  while (lo < hi) {
    int mid = (lo + hi) >> 1;
    if (batch[mid] < g + 1) lo = mid + 1; else hi = mid;
  }
  int end = lo;
  float b = bias[lane];
  float s1 = 0.f, s2 = 0.f;
  for (int n = start + w; n < end; n += 4) {
    float v = out_acc[(size_t)n * CC + lane] + b;
    s1 += v;
    s2 += v * v;
  }
  __shared__ float l1[4][64], l2[4][64];
  l1[w][lane] = s1;
  l2[w][lane] = s2;
  __syncthreads();
  if (w == 0) {
    s1 = l1[0][lane] + l1[1][lane] + l1[2][lane] + l1[3][lane];
    s2 = l2[0][lane] + l2[1][lane] + l2[2][lane] + l2[3][lane];
    float c = fmaxf((float)(end - start), 1.0f);
    float mean = s1 / c;
    float ms = mean * gns[lane];
    float var = s2 / c - 2.f * ms * mean + ms * ms;
    mean_s[g * CC + lane] = ms;
    istd[g * CC + lane] = rsqrtf(var + EPSV);
  }
}

// K7: normalize + affine + relu -> y
__global__ __launch_bounds__(256) void k_final(
    const int* __restrict__ batch, const float* __restrict__ out_acc,
    const float* __restrict__ bias, const float* __restrict__ mean_s,
    const float* __restrict__ istd, const float* __restrict__ gnw,
    const float* __restrict__ gnb, float* __restrict__ y) {
  int lane = threadIdx.x & 63;
  int n = blockIdx.x * 4 + (threadIdx.x >> 6);
  int g = batch[n];
  float v = out_acc[(size_t)n * CC + lane] + bias[lane];
  float o = (v - mean_s[g * CC + lane]) * istd[g * CC + lane];
  float r = gnw[lane] * o + gnb[lane];
  y[(size_t)n * CC + lane] = fmaxf(r, 0.0f);
}

extern "C" void kernel_launch(void* const* d_in, const int* in_sizes, int n_in,
                              void* d_out, int out_size, void* d_ws, size_t ws_size,
                              hipStream_t stream) {
  const float* node = (const float*)d_in[0];
  const int* ei = (const int*)d_in[1];
  const float* eatt = (const float*)d_in[2];
  const int* batch = (const int*)d_in[3];
  const float* W = (const float*)d_in[4];
  const float* We = (const float*)d_in[5];
  const float* att_src = (const float*)d_in[6];
  const float* att_dst = (const float*)d_in[7];
  const float* att_edge = (const float*)d_in[8];
  const float* bias = (const float*)d_in[9];
  const float* gnw = (const float*)d_in[10];
  const float* gnb = (const float*)d_in[11];
  const float* gns = (const float*)d_in[12];

  float* ws = (float*)d_ws;
  size_t off = 0;
  float* x = ws + off;        off += (size_t)NN * HC;   // 12.8M
  float* partial = ws + off;  off += (size_t)EE * HH;   // 3.2M
  float* a_src = ws + off;    off += (size_t)NN * HH;
  float* a_dst = ws + off;    off += (size_t)NN * HH;
  float* u_src = ws + off;    off += HC;
  float* u_dst = ws + off;    off += HC;
  float* v_edge = ws + off;   off += 64;
  float* mean_s = ws + off;   off += GG * CC;
  float* istd = ws + off;     off += GG * CC;
  float* out_acc = ws + off;  off += (size_t)NN * CC;   // 3.2M (fully written)
  int* iws = (int*)(ws + off);
  size_t ioff = 0;
  int* hist = iws + ioff;     ioff += NN;
  int* ptr = iws + ioff;      ioff += NN + 1;
  int* cursor = iws + ioff;   ioff += NN;
  int* eid = iws + ioff;      ioff += EE;

  hipMemsetAsync(hist, 0, NN * sizeof(int), stream);

  float* y_out = (float*)d_out;
  float* att_out = (float*)d_out + (size_t)NN * CC;

  k_prep<<<1, 256, 0, stream>>>(W, We, att_src, att_dst, att_edge, u_src, u_dst,
                                v_edge);
  k_attn_node<<<(NN + 255) / 256, 256, 0, stream>>>(node, u_src, u_dst, a_src,
                                                    a_dst);
  k_xproj<<<2048, 256, 0, stream>>>(node, W, x);
  k_edge1<<<(EE + 255) / 256, 256, 0, stream>>>(eatt, ei, a_src, v_edge, partial,
                                                hist);
  k_scan<<<1, SCAN_T, 0, stream>>>(hist, ptr, cursor);
  k_permute<<<(EE + 255) / 256, 256, 0, stream>>>(ei, cursor, eid);
  k_gat<<<NN / 4, 256, 0, stream>>>(ptr, eid, ei, partial, a_dst, x, out_acc,
                                    att_out);
  k_stats<<<GG, 256, 0, stream>>>(batch, out_acc, bias, gns, mean_s, istd);
  k_final<<<NN / 4, 256, 0, stream>>>(batch, out_acc, bias, mean_s, istd, gnw,
                                      gnb, y_out);
}

// Round 4
// 428.732 us; speedup vs baseline: 2.7471x; 1.5124x over previous
//
#include <hip/hip_runtime.h>
#include <math.h>

#define NN 50000
#define EE 800000
#define HH 4
#define CC 64
#define DE 16
#define GG 64
#define HC 256          // H*C
#define NEG 0.2f
#define EPSV 1e-5f
#define NB 196          // scan blocks: 196*256 = 50176 >= NN

__device__ __forceinline__ float bf2f(unsigned short u) {
  return __uint_as_float(((unsigned int)u) << 16);
}
__device__ __forceinline__ unsigned short f2bf(float f) {
  unsigned int x = __float_as_uint(f);
  unsigned int r = (x + 0x7fff + ((x >> 16) & 1)) >> 16;  // round-nearest-even
  return (unsigned short)r;
}
__device__ __forceinline__ float lrelu(float a) {
  return fmaxf(a, 0.f) + NEG * fminf(a, 0.f);
}

// K0: fold attention vectors through the projections.
__global__ __launch_bounds__(256) void k_prep(
    const float* __restrict__ W, const float* __restrict__ We,
    const float* __restrict__ as_, const float* __restrict__ ad_,
    const float* __restrict__ ae_,
    float* __restrict__ u_src, float* __restrict__ u_dst,
    float* __restrict__ v_edge) {
  int t = threadIdx.x;
  int k = t >> 2, h = t & 3;
  float s1 = 0.f, s2 = 0.f;
  for (int c = 0; c < CC; ++c) {
    float w = W[k * HC + h * CC + c];
    s1 += w * as_[h * CC + c];
    s2 += w * ad_[h * CC + c];
  }
  u_src[t] = s1;
  u_dst[t] = s2;
  if (t < DE * HH) {
    int d = t >> 2, hh = t & 3;
    float s3 = 0.f;
    for (int c = 0; c < CC; ++c) s3 += We[d * HC + hh * CC + c] * ae_[hh * CC + c];
    v_edge[t] = s3;
  }
}

// K1: x16[n][hc] = bf16( sum_k node[n][k] * W[k][hc] ). x consumed only by the
// k_gat gather -> store bf16 to halve the dominant gather stream.
__global__ __launch_bounds__(256) void k_xproj(
    const float* __restrict__ node, const float* __restrict__ W,
    unsigned short* __restrict__ x16) {
  int lane = threadIdx.x & 63;
  int wid = threadIdx.x >> 6;
  int hc = wid * 64 + lane;
  float wcol[CC];
#pragma unroll
  for (int k = 0; k < CC; ++k) wcol[k] = W[k * HC + hc];
  for (int n = blockIdx.x; n < NN; n += gridDim.x) {
    float nval = node[n * CC + lane];
    float acc = 0.f;
#pragma unroll
    for (int k = 0; k < CC; ++k) {
      float s = __uint_as_float(__builtin_amdgcn_readlane(__float_as_uint(nval), k));
      acc += s * wcol[k];
    }
    x16[(size_t)n * HC + hc] = f2bf(acc);
  }
}

// K1b: per-node attention logits via the folded u mats.
__global__ __launch_bounds__(256) void k_attn_node(
    const float* __restrict__ node, const float* __restrict__ u_src,
    const float* __restrict__ u_dst, float* __restrict__ a_src,
    float* __restrict__ a_dst) {
  __shared__ float us[HC], ud[HC];
  int t = threadIdx.x;
  us[t] = u_src[t];
  ud[t] = u_dst[t];
  __syncthreads();
  int n = blockIdx.x * 256 + t;
  if (n >= NN) return;
  const float4* n4 = (const float4*)(node + n * CC);
  float aS[4] = {0, 0, 0, 0}, aD[4] = {0, 0, 0, 0};
#pragma unroll
  for (int kk = 0; kk < 16; ++kk) {
    float4 nv = n4[kk];
    float nvs[4] = {nv.x, nv.y, nv.z, nv.w};
#pragma unroll
    for (int j = 0; j < 4; ++j) {
      int k = kk * 4 + j;
#pragma unroll
      for (int h = 0; h < 4; ++h) {
        aS[h] += nvs[j] * us[k * 4 + h];
        aD[h] += nvs[j] * ud[k * 4 + h];
      }
    }
  }
  *(float4*)(a_src + n * 4) = make_float4(aS[0], aS[1], aS[2], aS[3]);
  *(float4*)(a_dst + n * 4) = make_float4(aD[0], aD[1], aD[2], aD[3]);
}

// K2: per-edge PARTIAL logit (a_src[src] + edge_attr@v) + dst histogram.
__global__ __launch_bounds__(256) void k_edge1(
    const float* __restrict__ edge_attr, const int* __restrict__ ei,
    const float* __restrict__ a_src, const float* __restrict__ v_edge,
    float* __restrict__ partial, int* __restrict__ hist) {
  __shared__ float vs[DE * HH];
  int t = threadIdx.x;
  if (t < DE * HH) vs[t] = v_edge[t];
  __syncthreads();
  int e = blockIdx.x * 256 + t;
  if (e >= EE) return;
  const float4* ea4 = (const float4*)(edge_attr + (size_t)e * DE);
  float ae[4] = {0, 0, 0, 0};
#pragma unroll
  for (int dd = 0; dd < 4; ++dd) {
    float4 ev = ea4[dd];
    float evs[4] = {ev.x, ev.y, ev.z, ev.w};
#pragma unroll
    for (int j = 0; j < 4; ++j) {
      int d = dd * 4 + j;
#pragma unroll
      for (int h = 0; h < 4; ++h) ae[h] += evs[j] * vs[d * 4 + h];
    }
  }
  int sn = ei[e], dn = ei[EE + e];
  float4 as4 = *(const float4*)(a_src + (size_t)sn * 4);
  *(float4*)(partial + (size_t)e * 4) =
      make_float4(as4.x + ae[0], as4.y + ae[1], as4.z + ae[2], as4.w + ae[3]);
  atomicAdd(&hist[dn], 1);
}

// K3a: coalesced per-block sums of the histogram.
__global__ __launch_bounds__(256) void k_scanA(
    const int* __restrict__ hist, int* __restrict__ bsum) {
  __shared__ int s[256];
  int t = threadIdx.x;
  int idx = blockIdx.x * 256 + t;
  s[t] = (idx < NN) ? hist[idx] : 0;
  __syncthreads();
  for (int d = 128; d; d >>= 1) {
    if (t < d) s[t] += s[t + d];
    __syncthreads();
  }
  if (t == 0) bsum[blockIdx.x] = s[0];
}

// K3b: single block: exclusive scan of NB block sums.
__global__ __launch_bounds__(256) void k_scanB(
    const int* __restrict__ bsum, int* __restrict__ boff,
    int* __restrict__ ptr) {
  __shared__ int s[256];
  int t = threadIdx.x;
  int v = (t < NB) ? bsum[t] : 0;
  s[t] = v;
  __syncthreads();
  for (int d = 1; d < 256; d <<= 1) {
    int u = (t >= d) ? s[t - d] : 0;
    __syncthreads();
    s[t] += u;
    __syncthreads();
  }
  if (t < NB) boff[t] = s[t] - v;
  if (t == 255) ptr[NN] = s[255];
}

// K3c: per-block exclusive scan + block offset -> ptr, cursor. Coalesced.
__global__ __launch_bounds__(256) void k_scanC(
    const int* __restrict__ hist, const int* __restrict__ boff,
    int* __restrict__ ptr, int* __restrict__ cursor) {
  __shared__ int s[256];
  int t = threadIdx.x;
  int idx = blockIdx.x * 256 + t;
  int v = (idx < NN) ? hist[idx] : 0;
  s[t] = v;
  __syncthreads();
  for (int d = 1; d < 256; d <<= 1) {
    int u = (t >= d) ? s[t - d] : 0;
    __syncthreads();
    s[t] += u;
    __syncthreads();
  }
  if (idx < NN) {
    int p = boff[blockIdx.x] + s[t] - v;
    ptr[idx] = p;
    cursor[idx] = p;
  }
}

// K4: permute edges into dst-sorted order; carry partial logits + src id so
// k_gat reads contiguous runs.
__global__ __launch_bounds__(256) void k_permute(
    const int* __restrict__ ei, const float* __restrict__ partial,
    int* __restrict__ cursor, int* __restrict__ eid,
    float* __restrict__ psort, int* __restrict__ ssort) {
  int e = blockIdx.x * 256 + threadIdx.x;
  if (e >= EE) return;
  int sn = ei[e], dn = ei[EE + e];
  int pos = atomicAdd(&cursor[dn], 1);
  eid[pos] = e;
  ssort[pos] = sn;
  *(float4*)(psort + (size_t)pos * 4) = *(const float4*)(partial + (size_t)e * 4);
}

// K5: one wave per dst node, SINGLE merged pass (no max subtraction: logits
// are O(10), exp fine in fp32). Denominators accumulate wave-uniform; exp
// computed once per edge. Second lane-parallel loop writes att.
__global__ __launch_bounds__(256) void k_gat(
    const int* __restrict__ ptr, const int* __restrict__ eid,
    const int* __restrict__ ssort, const float* __restrict__ psort,
    const float* __restrict__ a_dst, const unsigned short* __restrict__ x16,
    float* __restrict__ out_acc, float* __restrict__ att_out) {
  int lane = threadIdx.x & 63;
  int w = threadIdx.x >> 6;
  int v = blockIdx.x * 4 + w;
  int start = ptr[v], end = ptr[v + 1];
  float4 ad = *(const float4*)(a_dst + (size_t)v * 4);
  float d0 = 0.f, d1 = 0.f, d2 = 0.f, d3 = 0.f;
  float acc0 = 0.f, acc1 = 0.f, acc2 = 0.f, acc3 = 0.f;
#pragma unroll 2
  for (int j = start; j < end; ++j) {
    float4 p = *(const float4*)(psort + (size_t)j * 4);
    int sn = ssort[j];
    float t0 = __expf(lrelu(p.x + ad.x));
    float t1 = __expf(lrelu(p.y + ad.y));
    float t2 = __expf(lrelu(p.z + ad.z));
    float t3 = __expf(lrelu(p.w + ad.w));
    d0 += t0; d1 += t1; d2 += t2; d3 += t3;
    const unsigned short* xs = x16 + (size_t)sn * HC;
    acc0 += t0 * bf2f(xs[lane]);
    acc1 += t1 * bf2f(xs[64 + lane]);
    acc2 += t2 * bf2f(xs[128 + lane]);
    acc3 += t3 * bf2f(xs[192 + lane]);
  }
  float r0 = 1.f / (d0 + 1e-16f), r1 = 1.f / (d1 + 1e-16f);
  float r2 = 1.f / (d2 + 1e-16f), r3 = 1.f / (d3 + 1e-16f);
  out_acc[(size_t)v * CC + lane] =
      0.25f * (r0 * acc0 + r1 * acc1 + r2 * acc2 + r3 * acc3);
  // att output, lane-parallel, recompute t from cached psort
  for (int j = start + lane; j < end; j += 64) {
    float4 p = *(const float4*)(psort + (size_t)j * 4);
    float t0 = __expf(lrelu(p.x + ad.x)) * r0;
    float t1 = __expf(lrelu(p.y + ad.y)) * r1;
    float t2 = __expf(lrelu(p.z + ad.z)) * r2;
    float t3 = __expf(lrelu(p.w + ad.w)) * r3;
    *(float4*)(att_out + (size_t)eid[j] * 4) = make_float4(t0, t1, t2, t3);
  }
}

// K6: GraphNorm stats, one block per group (batch sorted -> contiguous runs).
__global__ __launch_bounds__(256) void k_stats(
    const int* __restrict__ batch, const float* __restrict__ out_acc,
    const float* __restrict__ bias, const float* __restrict__ gns,
    float* __restrict__ mean_s, float* __restrict__ istd) {
  int g = blockIdx.x;
  int lane = threadIdx.x & 63;
  int w = threadIdx.x >> 6;
  int lo = 0, hi = NN;
  while (lo < hi) {
    int mid = (lo + hi) >> 1;
    if (batch[mid] < g) lo = mid + 1; else hi = mid;
  }
  int start = lo;
  hi = NN;
  while (lo < hi) {
    int mid = (lo + hi) >> 1;
    if (batch[mid] < g + 1) lo = mid + 1; else hi = mid;
  }
  int end = lo;
  float b = bias[lane];
  float s1 = 0.f, s2 = 0.f;
  for (int n = start + w; n < end; n += 4) {
    float v = out_acc[(size_t)n * CC + lane] + b;
    s1 += v;
    s2 += v * v;
  }
  __shared__ float l1[4][64], l2[4][64];
  l1[w][lane] = s1;
  l2[w][lane] = s2;
  __syncthreads();
  if (w == 0) {
    s1 = l1[0][lane] + l1[1][lane] + l1[2][lane] + l1[3][lane];
    s2 = l2[0][lane] + l2[1][lane] + l2[2][lane] + l2[3][lane];
    float c = fmaxf((float)(end - start), 1.0f);
    float mean = s1 / c;
    float ms = mean * gns[lane];
    float var = s2 / c - 2.f * ms * mean + ms * ms;
    mean_s[g * CC + lane] = ms;
    istd[g * CC + lane] = rsqrtf(var + EPSV);
  }
}

// K7: normalize + affine + relu -> y
__global__ __launch_bounds__(256) void k_final(
    const int* __restrict__ batch, const float* __restrict__ out_acc,
    const float* __restrict__ bias, const float* __restrict__ mean_s,
    const float* __restrict__ istd, const float* __restrict__ gnw,
    const float* __restrict__ gnb, float* __restrict__ y) {
  int lane = threadIdx.x & 63;
  int n = blockIdx.x * 4 + (threadIdx.x >> 6);
  int g = batch[n];
  float v = out_acc[(size_t)n * CC + lane] + bias[lane];
  float o = (v - mean_s[g * CC + lane]) * istd[g * CC + lane];
  float r = gnw[lane] * o + gnb[lane];
  y[(size_t)n * CC + lane] = fmaxf(r, 0.0f);
}

extern "C" void kernel_launch(void* const* d_in, const int* in_sizes, int n_in,
                              void* d_out, int out_size, void* d_ws, size_t ws_size,
                              hipStream_t stream) {
  const float* node = (const float*)d_in[0];
  const int* ei = (const int*)d_in[1];
  const float* eatt = (const float*)d_in[2];
  const int* batch = (const int*)d_in[3];
  const float* W = (const float*)d_in[4];
  const float* We = (const float*)d_in[5];
  const float* att_src = (const float*)d_in[6];
  const float* att_dst = (const float*)d_in[7];
  const float* att_edge = (const float*)d_in[8];
  const float* bias = (const float*)d_in[9];
  const float* gnw = (const float*)d_in[10];
  const float* gnb = (const float*)d_in[11];
  const float* gns = (const float*)d_in[12];

  float* ws = (float*)d_ws;
  size_t off = 0;
  float* partial = ws + off;  off += (size_t)EE * HH;   // 3.2M floats
  float* psort = ws + off;    off += (size_t)EE * HH;   // 3.2M
  float* a_src = ws + off;    off += (size_t)NN * HH;
  float* a_dst = ws + off;    off += (size_t)NN * HH;
  float* u_src = ws + off;    off += HC;
  float* u_dst = ws + off;    off += HC;
  float* v_edge = ws + off;   off += 64;
  float* mean_s = ws + off;   off += GG * CC;
  float* istd = ws + off;     off += GG * CC;
  float* out_acc = ws + off;  off += (size_t)NN * CC;
  unsigned short* x16 = (unsigned short*)(ws + off);
  off += (size_t)NN * HC / 2;                           // 12.8M ushort
  int* iws = (int*)(ws + off);
  size_t ioff = 0;
  int* hist = iws + ioff;     ioff += NN;
  int* ptr = iws + ioff;      ioff += NN + 1;
  int* cursor = iws + ioff;   ioff += NN;
  int* eid = iws + ioff;      ioff += EE;
  int* ssort = iws + ioff;    ioff += EE;
  int* bsum = iws + ioff;     ioff += NB;
  int* boff = iws + ioff;     ioff += NB;

  hipMemsetAsync(hist, 0, NN * sizeof(int), stream);

  float* y_out = (float*)d_out;
  float* att_out = (float*)d_out + (size_t)NN * CC;

  k_prep<<<1, 256, 0, stream>>>(W, We, att_src, att_dst, att_edge, u_src, u_dst,
                                v_edge);
  k_attn_node<<<(NN + 255) / 256, 256, 0, stream>>>(node, u_src, u_dst, a_src,
                                                    a_dst);
  k_xproj<<<2048, 256, 0, stream>>>(node, W, x16);
  k_edge1<<<(EE + 255) / 256, 256, 0, stream>>>(eatt, ei, a_src, v_edge, partial,
                                                hist);
  k_scanA<<<NB, 256, 0, stream>>>(hist, bsum);
  k_scanB<<<1, 256, 0, stream>>>(bsum, boff, ptr);
  k_scanC<<<NB, 256, 0, stream>>>(hist, boff, ptr, cursor);
  k_permute<<<(EE + 255) / 256, 256, 0, stream>>>(ei, partial, cursor, eid,
                                                  psort, ssort);
  k_gat<<<NN / 4, 256, 0, stream>>>(ptr, eid, ssort, psort, a_dst, x16, out_acc,
                                    att_out);
  k_stats<<<GG, 256, 0, stream>>>(batch, out_acc, bias, gns, mean_s, istd);
  k_final<<<NN / 4, 256, 0, stream>>>(batch, out_acc, bias, mean_s, istd, gnw,
                                      gnb, y_out);
}